// Round 16
// baseline (631.257 us; speedup 1.0000x reference)
//
#include <hip/hip_runtime.h>

typedef __attribute__((ext_vector_type(4))) float f32x4;
typedef __attribute__((ext_vector_type(2))) unsigned int u32x2;
typedef _Float16 f16x8 __attribute__((ext_vector_type(8)));
typedef _Float16 h2    __attribute__((ext_vector_type(2)));

#define TTOK 10000
#define SBAR() __builtin_amdgcn_sched_barrier(0)

__device__ __forceinline__ h2 pkh(float lo, float hi){
  auto t = __builtin_amdgcn_cvt_pkrtz(lo, hi);   // __fp16 x2 -> bitcast to h2
  union{ decltype(t) a; h2 b; } c; c.a = t; return c.b;
}
__device__ __forceinline__ unsigned h2u(h2 v){ union{h2 h; unsigned u;} c; c.h=v; return c.u; }

__device__ __forceinline__ unsigned short f2h(float f){
  _Float16 h = (_Float16)f;                 // RNE
  union{_Float16 h; unsigned short u;} c; c.h = h; return c.u;
}

// ---------------- prep: fragment-linear f16 weights, hb+t*tw seeds, c ----------------
// wb[((jj*4+kc)*64 + l)*8 + i] = W[jj*16+q][kc*32+g*8+i], l=g*16+q: a wave's
// 16B/lane fragment read is 64 lanes x contiguous = 1024B (conflict-free /
// fully coalesced), address = base + immediate (round 13, verified).
__global__ void cnf_prep(const float* __restrict__ h, const float* __restrict__ Wx,
                         const float* __restrict__ wxt, const float* __restrict__ bx,
                         const float* __restrict__ Wh, const float* __restrict__ wht,
                         const float* __restrict__ bh, const float* __restrict__ W2,
                         float* __restrict__ hbt, float* __restrict__ cv,
                         unsigned short* __restrict__ wxb, unsigned short* __restrict__ w2b)
{
  const int b = blockIdx.x, t = threadIdx.x;
  if (b < 16) {
    const int jj = b & 7;
    const float* W = (b < 8) ? Wx : W2;
    unsigned short* dst = (b < 8) ? wxb : w2b;
    const int kc = t>>6, l = t&63, q = l&15, g = l>>4;
    #pragma unroll
    for (int i=0;i<8;++i)
      dst[((jj*4+kc)*64 + l)*8 + i] = f2h(W[(jj*16+q)*128 + kc*32 + g*8 + i]);
  } else if (b < 18) {
    for (int i=0;i<4;++i){
      int idx = i*256 + t;
      int sb = (b-16)*8 + (idx>>7);
      int j  = idx & 127;
      float a = 0.f;
      for (int e2=0;e2<128;++e2) a += h[sb*128+e2]*Wh[j*128+e2];
      float base = a + bh[j] + bx[j];
      float tw   = wxt[j] + wht[j];
      for (int ti=0; ti<5; ++ti)
        hbt[(ti*16+sb)*128 + j] = base + 0.25f*(float)ti*tw;   // t in {0,.25,.5,.75,1}
    }
  } else {
    if (t < 128){
      float a = 0.f;
      for (int i=0;i<128;++i) a += W2[i*128+t]*Wx[t*128+i];
      cv[t] = a;
    }
  }
}

// ---------------- fused CNF main kernel ----------------
// Round-16 (= round-15 with type fix): round-14 nt=2 structure with
// (1) full f16 datapath — packed half2 state math (v_pk_fma_f16 /
// v_cvt_pkrtz) cuts ~90 VALU ops/eval, f16 MFMA same rate, better mantissa;
// (2) W2 read straight from L2 (fragment-linear, 1KB coalesced per read,
// prefetched under softplus) so LDS = 32KB Wx + 16KB bufs = 48KB ->
// 3 blocks/CU possible. (256,3): reg cap 170 -> no spill.
__global__ __launch_bounds__(256, 3) void cnf_main(
    const float* __restrict__ emb, const float* __restrict__ lp0,
    const float* __restrict__ b2g, const float* __restrict__ hbt,
    const float* __restrict__ cg,  const unsigned short* __restrict__ wxb,
    const unsigned short* __restrict__ w2b, float* __restrict__ out)
{
  __shared__ __align__(16) unsigned short sWx[16384];
  __shared__ __align__(16) unsigned short sT[4][2048];   // per-tile timeshared z^T/sp^T (4KB)

  const int tid = threadIdx.x;
  const int rowbase = blockIdx.x*64;

  // stage Wx into LDS: plain linear copy (layout already fragment-linear)
  for (int it=0; it<8; ++it){
    int L = it*4096 + tid*16;
    *(int4*)((char*)sWx + L) = *(const int4*)((const char*)wxb + L);
  }
  __syncthreads();

  const int w = tid>>6, tg = w>>1, hw = w&1, l = tid&63, q = l&15, g = l>>4;
  char* zB0 = (char*)&sT[2*tg][0];
  char* zB1 = (char*)&sT[2*tg+1][0];
  const char* wxBase = (const char*)sWx + hw*16384 + l*16;       // + (j*4+kc)*1024 imm
  const char* w2p    = (const char*)w2b + hw*16384 + l*16;       // global, L2-resident
  const int cwB = q*16 + 8*(g&1) + 256*(g>>1);  // transpose write base (bytes), + slot*512
  const int crB = g*256 + q*16;                 // transpose read base (bytes), + kc*1024
  const int hof = hw*64 + 4*g;                  // h/e base for this wave: + 16*j + r

  const int row0 = rowbase + tg*32 + q;
  const int row1 = row0 + 16;
  const int sb0 = row0/TTOK, tt0 = row0 - sb0*TTOK;
  const int sb1 = row1/TTOK, tt1 = row1 - sb1*TTOK;

  h2 zbp0[4][2], zbp1[4][2];   // z state, packed f16 (16 VGPRs)
  h2 ksp0[4][2], ksp1[4][2];   // RK4 running sum, packed f16 (16 VGPRs)
  f32x4 wk0[4], wk1[4];        // f32 accumulators
  f32x4 b2r[4];                // persistent b2
  float dlt0 = 0.f, dlt1 = 0.f;

  #pragma unroll
  for (int j=0; j<4; ++j){
    f32x4 e0 = *(const f32x4*)(emb + tt0*128 + hof + 16*j);
    f32x4 e1 = *(const f32x4*)(emb + tt1*128 + hof + 16*j);
    zbp0[j][0] = pkh(e0[0], e0[1]);
    zbp0[j][1] = pkh(e0[2], e0[3]);
    zbp1[j][0] = pkh(e1[0], e1[1]);
    zbp1[j][1] = pkh(e1[2], e1[3]);
    wk0[j] = (f32x4){0.f,0.f,0.f,0.f};
    wk1[j] = (f32x4){0.f,0.f,0.f,0.f};
    ksp0[j][0] = (h2){0,0}; ksp0[j][1] = (h2){0,0};
    ksp1[j][0] = (h2){0,0}; ksp1[j][1] = (h2){0,0};
    b2r[j] = *(const f32x4*)(b2g + hof + 16*j);
  }

  #pragma unroll 1
  for (int se=0; se<8; ++se){
    const int   s    = se>>2, e = se&3;
    const float coef = (e==0)?0.f:((e==3)?0.5f:0.25f); // z_eval = z_base + coef*k_prev
    const float we   = (e==1||e==2)?2.f:1.f;
    const int   ti   = 2*s + ((e==0)?0:((e<3)?1:2));
    const _Float16 ch = (_Float16)coef;
    const h2 coef2 = {ch, ch};
    const _Float16 wh_ = (_Float16)we;
    const h2 we2 = {wh_, wh_};
    const h2 c12 = {(_Float16)(1.f/12.f), (_Float16)(1.f/12.f)};

    // ---- phase 1: prefetch hb seeds; pack z_eval (both tiles) -> z^T buffers
    f32x4 hb0[4], hb1[4];
    {
      const float* p0 = hbt + (ti*16 + sb0)*128 + hof;
      const float* p1 = hbt + (ti*16 + sb1)*128 + hof;
      #pragma unroll
      for (int j=0; j<4; ++j){
        hb0[j] = *(const f32x4*)(p0 + 16*j);
        hb1[j] = *(const f32x4*)(p1 + 16*j);
      }
    }
    #pragma unroll
    for (int j=0; j<4; ++j){
      u32x2 wv0, wv1;
      if (e==0){
        wv0[0] = h2u(zbp0[j][0]); wv0[1] = h2u(zbp0[j][1]);
        wv1[0] = h2u(zbp1[j][0]); wv1[1] = h2u(zbp1[j][1]);
      } else {
        h2 a0 = pkh(wk0[j][0], wk0[j][1]);
        h2 a1 = pkh(wk0[j][2], wk0[j][3]);
        h2 z0 = coef2*a0 + zbp0[j][0];
        h2 z1 = coef2*a1 + zbp0[j][1];
        wv0[0] = h2u(z0); wv0[1] = h2u(z1);
        h2 b0 = pkh(wk1[j][0], wk1[j][1]);
        h2 b1 = pkh(wk1[j][2], wk1[j][3]);
        h2 y0 = coef2*b0 + zbp1[j][0];
        h2 y1 = coef2*b1 + zbp1[j][1];
        wv1[0] = h2u(y0); wv1[1] = h2u(y1);
      }
      int W = (hw*4+j)*512 + cwB;
      W ^= ((W>>8)&7)<<4;
      *(u32x2*)(zB0 + W) = wv0;
      *(u32x2*)(zB1 + W) = wv1;
    }
    SBAR();
    __syncthreads();   // z^T complete (both halves, both tiles)

    // ---- phase 3: matmul1 (h-half, both tiles): seed = prefetched hb
    #pragma unroll
    for (int j=0; j<4; ++j){ wk0[j] = hb0[j]; wk1[j] = hb1[j]; }
    #pragma unroll
    for (int kc=0; kc<4; ++kc){
      int R = kc*1024 + crB;
      R ^= ((R>>8)&7)<<4;
      f16x8 zf0 = *(const f16x8*)(zB0 + R);
      f16x8 zf1 = *(const f16x8*)(zB1 + R);
      #pragma unroll
      for (int j=0; j<4; ++j){
        f16x8 af = *(const f16x8*)(wxBase + (j*4+kc)*1024);
        wk0[j] = __builtin_amdgcn_mfma_f32_16x16x32_f16(af, zf0, wk0[j], 0,0,0);
        wk1[j] = __builtin_amdgcn_mfma_f32_16x16x32_f16(af, zf1, wk1[j], 0,0,0);
      }
      SBAR();
    }
    __syncthreads();   // z^T reads done; buffers free for sp^T

    // ---- phase 4: prefetch W2 frags kc0/1 (L2 latency hides under softplus);
    //               softplus both tiles -> sp^T buffers, sigmoid*c -> div
    f16x8 afA[4], afB[4];
    #pragma unroll
    for (int j=0; j<4; ++j) afA[j] = *(const f16x8*)(w2p + (j*4+0)*1024);
    #pragma unroll
    for (int j=0; j<4; ++j) afB[j] = *(const f16x8*)(w2p + (j*4+1)*1024);
    float dv0 = 0.f, dv1 = 0.f;
    #pragma unroll
    for (int j=0; j<4; ++j){
      f32x4 cc = *(const f32x4*)(cg + hof + 16*j);
      float sp0[4], sp1[4];
      #pragma unroll
      for (int r=0;r<4;++r){
        float x  = wk0[j][r];
        float ax = __builtin_fabsf(x);
        float ea = __expf(-ax);
        float opa = 1.0f + ea;
        float rc = __builtin_amdgcn_rcpf(opa);
        float lg = __logf(opa);
        sp0[r] = fmaxf(x,0.f) + lg;
        float sg = (x >= 0.f) ? rc : ea*rc;
        dv0 += sg*cc[r];
        float y  = wk1[j][r];
        float ay = __builtin_fabsf(y);
        float eb = __expf(-ay);
        float opb = 1.0f + eb;
        float rb = __builtin_amdgcn_rcpf(opb);
        float lb = __logf(opb);
        sp1[r] = fmaxf(y,0.f) + lb;
        float sh = (y >= 0.f) ? rb : eb*rb;
        dv1 += sh*cc[r];
      }
      int W = (hw*4+j)*512 + cwB;
      W ^= ((W>>8)&7)<<4;
      u32x2 wv0 = { h2u(pkh(sp0[0],sp0[1])), h2u(pkh(sp0[2],sp0[3])) };
      u32x2 wv1 = { h2u(pkh(sp1[0],sp1[1])), h2u(pkh(sp1[2],sp1[3])) };
      *(u32x2*)(zB0 + W) = wv0;
      *(u32x2*)(zB1 + W) = wv1;
    }
    dlt0 += we*dv0;
    dlt1 += we*dv1;
    SBAR();
    __syncthreads();   // sp^T complete

    // ---- phase 5: matmul2 (o-half, both tiles): W2 frags from L2, ping-pong
    #pragma unroll
    for (int j=0; j<4; ++j){ wk0[j] = b2r[j]; wk1[j] = b2r[j]; }
    #pragma unroll
    for (int kc=0; kc<4; ++kc){
      int R = kc*1024 + crB;
      R ^= ((R>>8)&7)<<4;
      f16x8 sf0 = *(const f16x8*)(zB0 + R);
      f16x8 sf1 = *(const f16x8*)(zB1 + R);
      #pragma unroll
      for (int j=0; j<4; ++j){
        f16x8 af = (kc&1) ? afB[j] : afA[j];
        wk0[j] = __builtin_amdgcn_mfma_f32_16x16x32_f16(af, sf0, wk0[j], 0,0,0);
        wk1[j] = __builtin_amdgcn_mfma_f32_16x16x32_f16(af, sf1, wk1[j], 0,0,0);
      }
      if (kc==0){
        #pragma unroll
        for (int j=0; j<4; ++j) afA[j] = *(const f16x8*)(w2p + (j*4+2)*1024);
      } else if (kc==1){
        #pragma unroll
        for (int j=0; j<4; ++j) afB[j] = *(const f16x8*)(w2p + (j*4+3)*1024);
      }
    }
    SBAR();

    // ---- phase 6: RK4 accumulate (both tiles; wk = k_e), packed f16
    if (e==0){
      #pragma unroll
      for (int j=0;j<4;++j){
        ksp0[j][0] = pkh(wk0[j][0], wk0[j][1]);
        ksp0[j][1] = pkh(wk0[j][2], wk0[j][3]);
        ksp1[j][0] = pkh(wk1[j][0], wk1[j][1]);
        ksp1[j][1] = pkh(wk1[j][2], wk1[j][3]);
      }
    } else if (e<3){
      #pragma unroll
      for (int j=0;j<4;++j){
        ksp0[j][0] = we2*pkh(wk0[j][0], wk0[j][1]) + ksp0[j][0];
        ksp0[j][1] = we2*pkh(wk0[j][2], wk0[j][3]) + ksp0[j][1];
        ksp1[j][0] = we2*pkh(wk1[j][0], wk1[j][1]) + ksp1[j][0];
        ksp1[j][1] = we2*pkh(wk1[j][2], wk1[j][3]) + ksp1[j][1];
      }
    } else {
      #pragma unroll
      for (int j=0;j<4;++j){
        h2 t00 = ksp0[j][0] + pkh(wk0[j][0], wk0[j][1]);
        h2 t01 = ksp0[j][1] + pkh(wk0[j][2], wk0[j][3]);
        zbp0[j][0] = c12*t00 + zbp0[j][0];
        zbp0[j][1] = c12*t01 + zbp0[j][1];
        h2 t10 = ksp1[j][0] + pkh(wk1[j][0], wk1[j][1]);
        h2 t11 = ksp1[j][1] + pkh(wk1[j][2], wk1[j][3]);
        zbp1[j][0] = c12*t10 + zbp1[j][0];
        zbp1[j][1] = c12*t11 + zbp1[j][1];
      }
    }
    SBAR();
    __syncthreads();   // sp^T reads done; buffers free for next eval's z^T
  }

  // ---- epilogue: g-reduce div partials, cross-wave combine via LDS (reuse zB0)
  {
    float d0 = dlt0, d1 = dlt1;
    d0 += __shfl_xor(d0, 16, 64);
    d0 += __shfl_xor(d0, 32, 64);
    d1 += __shfl_xor(d1, 16, 64);
    d1 += __shfl_xor(d1, 32, 64);
    float* fDv = (float*)zB0;
    if (g==0){
      fDv[hw*16 + q]      = d0;
      fDv[32 + hw*16 + q] = d1;
    }
    __syncthreads();
    if (hw==0 && g==0){
      float t0 = (fDv[q] + fDv[16+q]) * (1.f/12.f);
      float t1 = (fDv[32+q] + fDv[48+q]) * (1.f/12.f);
      out[row0] = lp0[row0] - t0;
      out[row1] = lp0[row1] - t1;
    }
  }
}

extern "C" void kernel_launch(void* const* d_in, const int* in_sizes, int n_in,
                              void* d_out, int out_size, void* d_ws, size_t ws_size,
                              hipStream_t stream) {
  const float* h    = (const float*)d_in[0];
  const float* emb  = (const float*)d_in[1];
  const float* lp0  = (const float*)d_in[2];
  const float* Wx   = (const float*)d_in[3];
  const float* wxt  = (const float*)d_in[4];
  const float* bx   = (const float*)d_in[5];
  const float* Wh   = (const float*)d_in[6];
  const float* wht  = (const float*)d_in[7];
  const float* bh   = (const float*)d_in[8];
  const float* W2   = (const float*)d_in[9];
  const float* b2   = (const float*)d_in[10];
  float* out = (float*)d_out;

  char* ws = (char*)d_ws;
  float* hbt          = (float*)ws;            // 5*16*128 f32 = 40960 B
  float* cv           = (float*)(ws + 40960);  // 128 f32     = 512 B
  unsigned short* wxb = (unsigned short*)(ws + 41472); // 16384 f16 = 32768 B
  unsigned short* w2b = (unsigned short*)(ws + 74240); // 16384 f16 = 32768 B

  cnf_prep<<<19, 256, 0, stream>>>(h, Wx, wxt, bx, Wh, wht, bh, W2, hbt, cv, wxb, w2b);
  cnf_main<<<2500, 256, 0, stream>>>(emb, lp0, b2, hbt, cv, wxb, w2b, out);
}

// Round 17
// 203.341 us; speedup vs baseline: 3.1044x; 3.1044x over previous
//
#include <hip/hip_runtime.h>

typedef __attribute__((ext_vector_type(4))) float f32x4;
typedef __attribute__((ext_vector_type(2))) unsigned int u32x2;
typedef _Float16 f16x8 __attribute__((ext_vector_type(8)));
typedef _Float16 h2    __attribute__((ext_vector_type(2)));

#define TTOK 10000
#define SBAR() __builtin_amdgcn_sched_barrier(0)

__device__ __forceinline__ h2 pkh(float lo, float hi){
  auto t = __builtin_amdgcn_cvt_pkrtz(lo, hi);   // __fp16 x2 -> bitcast to h2
  union{ decltype(t) a; h2 b; } c; c.a = t; return c.b;
}
__device__ __forceinline__ unsigned h2u(h2 v){ union{h2 h; unsigned u;} c; c.h=v; return c.u; }

__device__ __forceinline__ unsigned short f2h(float f){
  _Float16 h = (_Float16)f;                 // RNE
  union{_Float16 h; unsigned short u;} c; c.h = h; return c.u;
}

// ---------------- prep: fragment-linear f16 weights, hb+t*tw seeds, c ----------------
// wb[((jj*4+kc)*64 + l)*8 + i] = W[jj*16+q][kc*32+g*8+i], l=g*16+q: a wave's
// 16B/lane fragment read is 64 lanes x contiguous = 1024B (conflict-free),
// address = base + immediate (round 13, verified).
__global__ void cnf_prep(const float* __restrict__ h, const float* __restrict__ Wx,
                         const float* __restrict__ wxt, const float* __restrict__ bx,
                         const float* __restrict__ Wh, const float* __restrict__ wht,
                         const float* __restrict__ bh, const float* __restrict__ W2,
                         float* __restrict__ hbt, float* __restrict__ cv,
                         unsigned short* __restrict__ wxb, unsigned short* __restrict__ w2b)
{
  const int b = blockIdx.x, t = threadIdx.x;
  if (b < 16) {
    const int jj = b & 7;
    const float* W = (b < 8) ? Wx : W2;
    unsigned short* dst = (b < 8) ? wxb : w2b;
    const int kc = t>>6, l = t&63, q = l&15, g = l>>4;
    #pragma unroll
    for (int i=0;i<8;++i)
      dst[((jj*4+kc)*64 + l)*8 + i] = f2h(W[(jj*16+q)*128 + kc*32 + g*8 + i]);
  } else if (b < 18) {
    for (int i=0;i<4;++i){
      int idx = i*256 + t;
      int sb = (b-16)*8 + (idx>>7);
      int j  = idx & 127;
      float a = 0.f;
      for (int e2=0;e2<128;++e2) a += h[sb*128+e2]*Wh[j*128+e2];
      float base = a + bh[j] + bx[j];
      float tw   = wxt[j] + wht[j];
      for (int ti=0; ti<5; ++ti)
        hbt[(ti*16+sb)*128 + j] = base + 0.25f*(float)ti*tw;   // t in {0,.25,.5,.75,1}
    }
  } else {
    if (t < 128){
      float a = 0.f;
      for (int i=0;i<128;++i) a += W2[i*128+t]*Wx[t*128+i];
      cv[t] = a;
    }
  }
}

// ---------------- fused CNF main kernel ----------------
// Round-17 = round-14 champion structure (nt=2, BOTH weights in LDS — round
// 16 proved W2-from-global costs 1.3GB of HBM re-reads) + f16 packed
// datapath (v_pk_fma_f16 state math, f16 MFMA, VGPR 84 in round 16).
// LDS 64KB weights + 16KB bufs = 80KB -> 2 blocks/CU.
__global__ __launch_bounds__(256, 2) void cnf_main(
    const float* __restrict__ emb, const float* __restrict__ lp0,
    const float* __restrict__ b2g, const float* __restrict__ hbt,
    const float* __restrict__ cg,  const unsigned short* __restrict__ wxb,
    const unsigned short* __restrict__ w2b, float* __restrict__ out)
{
  __shared__ __align__(16) unsigned short sWx[16384];
  __shared__ __align__(16) unsigned short sW2[16384];
  __shared__ __align__(16) unsigned short sT[4][2048];   // per-tile timeshared z^T/sp^T (4KB)

  const int tid = threadIdx.x;
  const int rowbase = blockIdx.x*64;

  // stage weights into LDS: plain linear copy (layout already fragment-linear)
  for (int it=0; it<8; ++it){
    int L = it*4096 + tid*16;
    *(int4*)((char*)sWx + L) = *(const int4*)((const char*)wxb + L);
    *(int4*)((char*)sW2 + L) = *(const int4*)((const char*)w2b + L);
  }
  __syncthreads();

  const int w = tid>>6, tg = w>>1, hw = w&1, l = tid&63, q = l&15, g = l>>4;
  char* zB0 = (char*)&sT[2*tg][0];
  char* zB1 = (char*)&sT[2*tg+1][0];
  const char* wxBase = (const char*)sWx + hw*16384 + l*16;  // + (j*4+kc)*1024 imm
  const char* w2Base = (const char*)sW2 + hw*16384 + l*16;
  const int cwB = q*16 + 8*(g&1) + 256*(g>>1);  // transpose write base (bytes), + slot*512
  const int crB = g*256 + q*16;                 // transpose read base (bytes), + kc*1024
  const int hof = hw*64 + 4*g;                  // h/e base for this wave: + 16*j + r

  const int row0 = rowbase + tg*32 + q;
  const int row1 = row0 + 16;
  const int sb0 = row0/TTOK, tt0 = row0 - sb0*TTOK;
  const int sb1 = row1/TTOK, tt1 = row1 - sb1*TTOK;

  h2 zbp0[4][2], zbp1[4][2];   // z state, packed f16 (16 VGPRs)
  h2 ksp0[4][2], ksp1[4][2];   // RK4 running sum, packed f16 (16 VGPRs)
  f32x4 wk0[4], wk1[4];        // f32 accumulators
  f32x4 b2r[4];                // persistent b2
  float dlt0 = 0.f, dlt1 = 0.f;

  #pragma unroll
  for (int j=0; j<4; ++j){
    f32x4 e0 = *(const f32x4*)(emb + tt0*128 + hof + 16*j);
    f32x4 e1 = *(const f32x4*)(emb + tt1*128 + hof + 16*j);
    zbp0[j][0] = pkh(e0[0], e0[1]);
    zbp0[j][1] = pkh(e0[2], e0[3]);
    zbp1[j][0] = pkh(e1[0], e1[1]);
    zbp1[j][1] = pkh(e1[2], e1[3]);
    wk0[j] = (f32x4){0.f,0.f,0.f,0.f};
    wk1[j] = (f32x4){0.f,0.f,0.f,0.f};
    ksp0[j][0] = (h2){0,0}; ksp0[j][1] = (h2){0,0};
    ksp1[j][0] = (h2){0,0}; ksp1[j][1] = (h2){0,0};
    b2r[j] = *(const f32x4*)(b2g + hof + 16*j);
  }

  #pragma unroll 1
  for (int se=0; se<8; ++se){
    const int   s    = se>>2, e = se&3;
    const float coef = (e==0)?0.f:((e==3)?0.5f:0.25f); // z_eval = z_base + coef*k_prev
    const float we   = (e==1||e==2)?2.f:1.f;
    const int   ti   = 2*s + ((e==0)?0:((e<3)?1:2));
    const _Float16 ch = (_Float16)coef;
    const h2 coef2 = {ch, ch};
    const _Float16 wh_ = (_Float16)we;
    const h2 we2 = {wh_, wh_};
    const h2 c12 = {(_Float16)(1.f/12.f), (_Float16)(1.f/12.f)};

    // ---- phase 1: prefetch hb seeds; pack z_eval (both tiles) -> z^T buffers
    f32x4 hb0[4], hb1[4];
    {
      const float* p0 = hbt + (ti*16 + sb0)*128 + hof;
      const float* p1 = hbt + (ti*16 + sb1)*128 + hof;
      #pragma unroll
      for (int j=0; j<4; ++j){
        hb0[j] = *(const f32x4*)(p0 + 16*j);
        hb1[j] = *(const f32x4*)(p1 + 16*j);
      }
    }
    #pragma unroll
    for (int j=0; j<4; ++j){
      u32x2 wv0, wv1;
      if (e==0){
        wv0[0] = h2u(zbp0[j][0]); wv0[1] = h2u(zbp0[j][1]);
        wv1[0] = h2u(zbp1[j][0]); wv1[1] = h2u(zbp1[j][1]);
      } else {
        h2 a0 = pkh(wk0[j][0], wk0[j][1]);
        h2 a1 = pkh(wk0[j][2], wk0[j][3]);
        h2 z0 = coef2*a0 + zbp0[j][0];
        h2 z1 = coef2*a1 + zbp0[j][1];
        wv0[0] = h2u(z0); wv0[1] = h2u(z1);
        h2 b0 = pkh(wk1[j][0], wk1[j][1]);
        h2 b1 = pkh(wk1[j][2], wk1[j][3]);
        h2 y0 = coef2*b0 + zbp1[j][0];
        h2 y1 = coef2*b1 + zbp1[j][1];
        wv1[0] = h2u(y0); wv1[1] = h2u(y1);
      }
      int W = (hw*4+j)*512 + cwB;
      W ^= ((W>>8)&7)<<4;
      *(u32x2*)(zB0 + W) = wv0;
      *(u32x2*)(zB1 + W) = wv1;
    }
    SBAR();
    __syncthreads();   // z^T complete (both halves, both tiles)

    // ---- phase 3: matmul1 (h-half, both tiles): seed = prefetched hb
    #pragma unroll
    for (int j=0; j<4; ++j){ wk0[j] = hb0[j]; wk1[j] = hb1[j]; }
    #pragma unroll
    for (int kc=0; kc<4; ++kc){
      int R = kc*1024 + crB;
      R ^= ((R>>8)&7)<<4;
      f16x8 zf0 = *(const f16x8*)(zB0 + R);
      f16x8 zf1 = *(const f16x8*)(zB1 + R);
      #pragma unroll
      for (int j=0; j<4; ++j){
        f16x8 af = *(const f16x8*)(wxBase + (j*4+kc)*1024);
        wk0[j] = __builtin_amdgcn_mfma_f32_16x16x32_f16(af, zf0, wk0[j], 0,0,0);
        wk1[j] = __builtin_amdgcn_mfma_f32_16x16x32_f16(af, zf1, wk1[j], 0,0,0);
      }
      SBAR();
    }
    __syncthreads();   // z^T reads done; buffers free for sp^T

    // ---- phase 4: softplus both tiles -> sp^T buffers, sigmoid*c -> div
    float dv0 = 0.f, dv1 = 0.f;
    #pragma unroll
    for (int j=0; j<4; ++j){
      f32x4 cc = *(const f32x4*)(cg + hof + 16*j);
      float sp0[4], sp1[4];
      #pragma unroll
      for (int r=0;r<4;++r){
        float x  = wk0[j][r];
        float ax = __builtin_fabsf(x);
        float ea = __expf(-ax);
        float opa = 1.0f + ea;
        float rc = __builtin_amdgcn_rcpf(opa);
        float lg = __logf(opa);
        sp0[r] = fmaxf(x,0.f) + lg;
        float sg = (x >= 0.f) ? rc : ea*rc;
        dv0 += sg*cc[r];
        float y  = wk1[j][r];
        float ay = __builtin_fabsf(y);
        float eb = __expf(-ay);
        float opb = 1.0f + eb;
        float rb = __builtin_amdgcn_rcpf(opb);
        float lb = __logf(opb);
        sp1[r] = fmaxf(y,0.f) + lb;
        float sh = (y >= 0.f) ? rb : eb*rb;
        dv1 += sh*cc[r];
      }
      int W = (hw*4+j)*512 + cwB;
      W ^= ((W>>8)&7)<<4;
      u32x2 wv0 = { h2u(pkh(sp0[0],sp0[1])), h2u(pkh(sp0[2],sp0[3])) };
      u32x2 wv1 = { h2u(pkh(sp1[0],sp1[1])), h2u(pkh(sp1[2],sp1[3])) };
      *(u32x2*)(zB0 + W) = wv0;
      *(u32x2*)(zB1 + W) = wv1;
    }
    dlt0 += we*dv0;
    dlt1 += we*dv1;
    SBAR();
    __syncthreads();   // sp^T complete

    // ---- phase 5: matmul2 (o-half, both tiles): seed = persistent b2
    #pragma unroll
    for (int j=0; j<4; ++j){ wk0[j] = b2r[j]; wk1[j] = b2r[j]; }
    #pragma unroll
    for (int kc=0; kc<4; ++kc){
      int R = kc*1024 + crB;
      R ^= ((R>>8)&7)<<4;
      f16x8 sf0 = *(const f16x8*)(zB0 + R);
      f16x8 sf1 = *(const f16x8*)(zB1 + R);
      #pragma unroll
      for (int j=0; j<4; ++j){
        f16x8 af = *(const f16x8*)(w2Base + (j*4+kc)*1024);
        wk0[j] = __builtin_amdgcn_mfma_f32_16x16x32_f16(af, sf0, wk0[j], 0,0,0);
        wk1[j] = __builtin_amdgcn_mfma_f32_16x16x32_f16(af, sf1, wk1[j], 0,0,0);
      }
      SBAR();
    }

    // ---- phase 6: RK4 accumulate (both tiles; wk = k_e), packed f16
    if (e==0){
      #pragma unroll
      for (int j=0;j<4;++j){
        ksp0[j][0] = pkh(wk0[j][0], wk0[j][1]);
        ksp0[j][1] = pkh(wk0[j][2], wk0[j][3]);
        ksp1[j][0] = pkh(wk1[j][0], wk1[j][1]);
        ksp1[j][1] = pkh(wk1[j][2], wk1[j][3]);
      }
    } else if (e<3){
      #pragma unroll
      for (int j=0;j<4;++j){
        ksp0[j][0] = we2*pkh(wk0[j][0], wk0[j][1]) + ksp0[j][0];
        ksp0[j][1] = we2*pkh(wk0[j][2], wk0[j][3]) + ksp0[j][1];
        ksp1[j][0] = we2*pkh(wk1[j][0], wk1[j][1]) + ksp1[j][0];
        ksp1[j][1] = we2*pkh(wk1[j][2], wk1[j][3]) + ksp1[j][1];
      }
    } else {
      #pragma unroll
      for (int j=0;j<4;++j){
        h2 t00 = ksp0[j][0] + pkh(wk0[j][0], wk0[j][1]);
        h2 t01 = ksp0[j][1] + pkh(wk0[j][2], wk0[j][3]);
        zbp0[j][0] = c12*t00 + zbp0[j][0];
        zbp0[j][1] = c12*t01 + zbp0[j][1];
        h2 t10 = ksp1[j][0] + pkh(wk1[j][0], wk1[j][1]);
        h2 t11 = ksp1[j][1] + pkh(wk1[j][2], wk1[j][3]);
        zbp1[j][0] = c12*t10 + zbp1[j][0];
        zbp1[j][1] = c12*t11 + zbp1[j][1];
      }
    }
    SBAR();
    __syncthreads();   // sp^T reads done; buffers free for next eval's z^T
  }

  // ---- epilogue: g-reduce div partials, cross-wave combine via LDS (reuse zB0)
  {
    float d0 = dlt0, d1 = dlt1;
    d0 += __shfl_xor(d0, 16, 64);
    d0 += __shfl_xor(d0, 32, 64);
    d1 += __shfl_xor(d1, 16, 64);
    d1 += __shfl_xor(d1, 32, 64);
    float* fDv = (float*)zB0;
    if (g==0){
      fDv[hw*16 + q]      = d0;
      fDv[32 + hw*16 + q] = d1;
    }
    __syncthreads();
    if (hw==0 && g==0){
      float t0 = (fDv[q] + fDv[16+q]) * (1.f/12.f);
      float t1 = (fDv[32+q] + fDv[48+q]) * (1.f/12.f);
      out[row0] = lp0[row0] - t0;
      out[row1] = lp0[row1] - t1;
    }
  }
}

extern "C" void kernel_launch(void* const* d_in, const int* in_sizes, int n_in,
                              void* d_out, int out_size, void* d_ws, size_t ws_size,
                              hipStream_t stream) {
  const float* h    = (const float*)d_in[0];
  const float* emb  = (const float*)d_in[1];
  const float* lp0  = (const float*)d_in[2];
  const float* Wx   = (const float*)d_in[3];
  const float* wxt  = (const float*)d_in[4];
  const float* bx   = (const float*)d_in[5];
  const float* Wh   = (const float*)d_in[6];
  const float* wht  = (const float*)d_in[7];
  const float* bh   = (const float*)d_in[8];
  const float* W2   = (const float*)d_in[9];
  const float* b2   = (const float*)d_in[10];
  float* out = (float*)d_out;

  char* ws = (char*)d_ws;
  float* hbt          = (float*)ws;            // 5*16*128 f32 = 40960 B
  float* cv           = (float*)(ws + 40960);  // 128 f32     = 512 B
  unsigned short* wxb = (unsigned short*)(ws + 41472); // 16384 f16 = 32768 B
  unsigned short* w2b = (unsigned short*)(ws + 74240); // 16384 f16 = 32768 B

  cnf_prep<<<19, 256, 0, stream>>>(h, Wx, wxt, bx, Wh, wht, bh, W2, hbt, cv, wxb, w2b);
  cnf_main<<<2500, 256, 0, stream>>>(emb, lp0, b2, hbt, cv, wxb, w2b, out);
}